// Round 6
// baseline (52.224 us; speedup 1.0000x reference)
//
#include <hip/hip_runtime.h>
#include <stdint.h>

#define N_ROWS 8192
#define DIM 256

constexpr float INV_T  = 1.0f / 0.07f;
constexpr float M0     = 1.0f / 0.07f;             // fixed LSE max: |cos| <= ~1
constexpr float LOG2E  = 1.44269504088896f;
constexpr float C1     = INV_T * LOG2E;            // exp arg scale (exp2 domain)
constexpr float C0     = -M0 * LOG2E;              // exp arg bias

typedef __bf16 bf16x8 __attribute__((ext_vector_type(8)));
typedef float  f32x4  __attribute__((ext_vector_type(4)));

__device__ inline unsigned short f32_to_bf16(float f) {
    union { float f; uint32_t u; } v; v.f = f;
    uint32_t u = v.u;
    u += 0x7FFFu + ((u >> 16) & 1u);   // round-to-nearest-even
    return (unsigned short)(u >> 16);
}

// Raw hardware exp2: args in [-28.6, 0.03] (normal range), ~1 ulp.
__device__ inline float fast_exp2(float x) {
    float r;
    asm("v_exp_f32 %0, %1" : "=v"(r) : "v"(x));
    return r;
}

// ---------------- Kernel 1: normalize rows -> bf16, l_pos ----------------
__global__ __launch_bounds__(256) void prep_kernel(
    const float* __restrict__ q, const float* __restrict__ k,
    unsigned short* __restrict__ qb, unsigned short* __restrict__ kb,
    float* __restrict__ lposT) {
    const int wid  = threadIdx.x >> 6;
    const int lane = threadIdx.x & 63;
    const int row  = blockIdx.x * 4 + wid;

    const float4 qv = *reinterpret_cast<const float4*>(q + (size_t)row * DIM + lane * 4);
    const float4 kv = *reinterpret_cast<const float4*>(k + (size_t)row * DIM + lane * 4);

    float qq = qv.x*qv.x + qv.y*qv.y + qv.z*qv.z + qv.w*qv.w;
    float kk = kv.x*kv.x + kv.y*kv.y + kv.z*kv.z + kv.w*kv.w;
    float qk = qv.x*kv.x + qv.y*kv.y + qv.z*kv.z + qv.w*kv.w;

    #pragma unroll
    for (int off = 32; off > 0; off >>= 1) {
        qq += __shfl_xor(qq, off, 64);
        kk += __shfl_xor(kk, off, 64);
        qk += __shfl_xor(qk, off, 64);
    }
    const float iq = 1.0f / sqrtf(qq);
    const float ik = 1.0f / sqrtf(kk);

    ushort4 qs, ks;
    qs.x = f32_to_bf16(qv.x * iq); qs.y = f32_to_bf16(qv.y * iq);
    qs.z = f32_to_bf16(qv.z * iq); qs.w = f32_to_bf16(qv.w * iq);
    ks.x = f32_to_bf16(kv.x * ik); ks.y = f32_to_bf16(kv.y * ik);
    ks.z = f32_to_bf16(kv.z * ik); ks.w = f32_to_bf16(kv.w * ik);
    *reinterpret_cast<ushort4*>(qb + (size_t)row * DIM + lane * 4) = qs;
    *reinterpret_cast<ushort4*>(kb + (size_t)row * DIM + lane * 4) = ks;

    if (lane == 0) lposT[row] = qk * iq * ik * INV_T;
}

// ---------------- Kernel 2: persistent K-strip GEMM + fused exp-sum ----------
// A = K rows (LDS), B = Q rows (registers, UNIQUE per wave: 32 rows each).
// Wave computes full 64-row K tile x its 32 Q rows -> per-Q-row sums are
// wave-local (no cross-wave reduction). LDS tile = 64 Krows x 128 dims (16KB),
// double-buffered; counted-vmcnt(4) 2-barrier steps; epilogue deferred 1 chunk;
// setprio(1) around MFMA clusters.
__global__ __launch_bounds__(256, 2) void gemm_lse_kernel(
    const unsigned short* __restrict__ qb, const unsigned short* __restrict__ kb,
    float* __restrict__ ps) {
    __shared__ char lds[2 * 16384];
    char* const b0 = lds;
    char* const b1 = lds + 16384;

    const int tid  = threadIdx.x;
    const int lane = tid & 63;
    const int wid  = tid >> 6;
    const int g    = lane >> 4;      // 0..3
    const int r16  = lane & 15;
    const int xr   = r16 & 7;

    const int strip   = blockIdx.x;        // 0..15 (x%8 -> XCD by dispatch order)
    const int qtile   = blockIdx.y;        // 0..63
    const int qbase   = qtile * 128;
    const int qw      = qbase + wid * 32;  // this wave's 32 unique Q rows
    const int kstrip0 = strip * 512;

    // staging map: issue i covers K rows [i*16, i*16+16); within it wave wid
    // owns rows wid*4 + (lane>>4), slot lane&15 (pre-swizzled source).
    const int srw    = lane >> 4;                       // 0..3
    const int rowmod = (wid * 4 + srw) & 7;
    const int sslot  = (lane & 15) ^ rowmod;            // inverse-swizzle SOURCE
    const int ldsOff = wid * 1024;

    auto stage = [&](int krow0, int dim0, char* dst) {
        #pragma unroll
        for (int i = 0; i < 4; ++i) {
            const unsigned short* gp =
                kb + (size_t)(krow0 + i * 16 + wid * 4 + srw) * DIM + dim0 + sslot * 8;
            __builtin_amdgcn_global_load_lds(
                (const __attribute__((address_space(1))) void*)gp,
                (__attribute__((address_space(3))) void*)(dst + i * 4096 + ldsOff),
                16, 0, 0);
        }
    };

    // ---- Q fragments straight from global (L2-resident, 16 x 16B per lane) ----
    bf16x8 qf[8][2];   // [dim-slice 0..7][j: 16-row half]
    #pragma unroll
    for (int s = 0; s < 8; ++s)
        #pragma unroll
        for (int j = 0; j < 2; ++j)
            qf[s][j] = *reinterpret_cast<const bf16x8*>(
                qb + (size_t)(qw + j * 16 + r16) * DIM + s * 32 + g * 8);
    __builtin_amdgcn_sched_barrier(0);     // keep qf loads before tile stages

    stage(kstrip0, 0, b0);                 // tile 0 (chunk 0, dims 0:128)
    __builtin_amdgcn_sched_barrier(0);

    f32x4 acc[4][2] = {};                  // [i: Krow/16][j]
    float ssum[2] = {0.f, 0.f};

    // one kstep: 64 K rows x 128 dims from LDS, slices sbase..sbase+3 of qf
    auto mfma_kstep = [&](const char* src, int sbase) {
        #pragma unroll
        for (int kk = 0; kk < 4; ++kk) {
            bf16x8 a[4];
            #pragma unroll
            for (int i = 0; i < 4; ++i)
                a[i] = *reinterpret_cast<const bf16x8*>(
                    src + (i * 16 + r16) * 256 + ((((kk << 2) | g) ^ xr) << 4));
            #pragma unroll
            for (int i = 0; i < 4; ++i)
                #pragma unroll
                for (int j = 0; j < 2; ++j)
                    acc[i][j] = __builtin_amdgcn_mfma_f32_16x16x32_bf16(
                        a[i], qf[sbase + kk][j], acc[i][j], 0, 0, 0);
        }
    };

    // deferred per-chunk epilogue: exp-accumulate acc (64 Krows done), zero acc
    auto epilogue = [&](int c) {
        const int kc0  = kstrip0 + c * 64;
        const bool diag = (kc0 >> 6) == (qw >> 6);   // wave-uniform
        #pragma unroll
        for (int j = 0; j < 2; ++j) {
            float s = 0.f;
            if (diag) {
                const int grow = qw + j * 16 + r16;
                #pragma unroll
                for (int i = 0; i < 4; ++i)
                    #pragma unroll
                    for (int r = 0; r < 4; ++r) {
                        float e = fast_exp2(fmaf(acc[i][j][r], C1, C0));
                        if (grow == kc0 + i * 16 + g * 4 + r) e = 0.f;
                        s += e;
                    }
            } else {
                #pragma unroll
                for (int i = 0; i < 4; ++i)
                    #pragma unroll
                    for (int r = 0; r < 4; ++r)
                        s += fast_exp2(fmaf(acc[i][j][r], C1, C0));
            }
            ssum[j] += s;
        }
        #pragma unroll
        for (int i = 0; i < 4; ++i) {
            acc[i][0] = f32x4{0.f, 0.f, 0.f, 0.f};
            acc[i][1] = f32x4{0.f, 0.f, 0.f, 0.f};
        }
    };

    // ---- main loop: chunks 0..6 (steady), chunk 7 peeled ----
    #pragma unroll 1
    for (int c = 0; c < 7; ++c) {
        stage(kstrip0 + c * 64, 128, b1);              // tile 2c+1
        asm volatile("s_waitcnt vmcnt(4)" ::: "memory");
        __builtin_amdgcn_s_barrier();
        __builtin_amdgcn_sched_barrier(0);
        if (c) epilogue(c - 1);
        __builtin_amdgcn_s_setprio(1);
        mfma_kstep(b0, 0);
        __builtin_amdgcn_s_setprio(0);
        __builtin_amdgcn_s_barrier();

        stage(kstrip0 + (c + 1) * 64, 0, b0);          // tile 2c+2
        asm volatile("s_waitcnt vmcnt(4)" ::: "memory");
        __builtin_amdgcn_s_barrier();
        __builtin_amdgcn_sched_barrier(0);
        __builtin_amdgcn_s_setprio(1);
        mfma_kstep(b1, 4);
        __builtin_amdgcn_s_setprio(0);
        __builtin_amdgcn_s_barrier();
    }
    // chunk 7
    stage(kstrip0 + 7 * 64, 128, b1);                  // tile 15
    asm volatile("s_waitcnt vmcnt(4)" ::: "memory");
    __builtin_amdgcn_s_barrier();
    __builtin_amdgcn_sched_barrier(0);
    epilogue(6);
    __builtin_amdgcn_s_setprio(1);
    mfma_kstep(b0, 0);
    __builtin_amdgcn_s_setprio(0);
    __builtin_amdgcn_s_barrier();
    asm volatile("s_waitcnt vmcnt(0)" ::: "memory");
    __builtin_amdgcn_s_barrier();
    __builtin_amdgcn_sched_barrier(0);
    __builtin_amdgcn_s_setprio(1);
    mfma_kstep(b1, 4);
    __builtin_amdgcn_s_setprio(0);
    epilogue(7);

    // ---- wave-local reduction over g-groups, direct store ----
    #pragma unroll
    for (int j = 0; j < 2; ++j) {
        float s = ssum[j];
        s += __shfl_xor(s, 16, 64);
        s += __shfl_xor(s, 32, 64);
        if (g == 0)
            ps[(size_t)(qw + j * 16 + r16) * 16 + strip] = s;
    }
}

// ---------------- Kernel 3: combine 16 strip partials -> loss ----------------
__global__ __launch_bounds__(256) void finalize_kernel(
    const float* __restrict__ ps, const float* __restrict__ lposT,
    float* __restrict__ out) {
    const int row = blockIdx.x * 256 + threadIdx.x;
    float S = 0.f;
    #pragma unroll
    for (int c = 0; c < 4; ++c) {
        const float4 p = *reinterpret_cast<const float4*>(ps + (size_t)row * 16 + c * 4);
        S += p.x + p.y + p.z + p.w;
    }
    const float lp = lposT[row];
    S += __expf(lp - M0);
    out[row] = M0 + logf(S) - lp;
}

extern "C" void kernel_launch(void* const* d_in, const int* in_sizes, int n_in,
                              void* d_out, int out_size, void* d_ws, size_t ws_size,
                              hipStream_t stream) {
    const float* q = (const float*)d_in[0];
    const float* k = (const float*)d_in[1];
    float* out = (float*)d_out;

    char* ws = (char*)d_ws;
    unsigned short* qb  = (unsigned short*)(ws);                      // 4 MB
    unsigned short* kb  = (unsigned short*)(ws + (4u << 20));         // 4 MB
    float*          lpt = (float*)(ws + (8u << 20));                  // 32 KB
    float*          ps  = (float*)(ws + (8u << 20) + (32u << 10));    // 512 KB

    prep_kernel<<<N_ROWS / 4, 256, 0, stream>>>(q, k, qb, kb, lpt);
    dim3 grid(16, 64);   // x = strip (x%8 -> XCD), y = Q-tile
    gemm_lse_kernel<<<grid, 256, 0, stream>>>(qb, kb, ps);
    finalize_kernel<<<N_ROWS / 256, 256, 0, stream>>>(ps, lpt, out);
}

// Round 7
// 49.979 us; speedup vs baseline: 1.0449x; 1.0449x over previous
//
#include <hip/hip_runtime.h>
#include <stdint.h>

#define N_ROWS 8192
#define DIM 256

constexpr float INV_T  = 1.0f / 0.07f;
constexpr float M0     = 1.0f / 0.07f;             // fixed LSE max: |cos| <= ~1
constexpr float LOG2E  = 1.44269504088896f;
constexpr float C1     = INV_T * LOG2E;            // exp arg scale (exp2 domain)
constexpr float C0     = -M0 * LOG2E;              // exp arg bias

typedef __bf16 bf16x8 __attribute__((ext_vector_type(8)));
typedef float  f32x4  __attribute__((ext_vector_type(4)));

__device__ inline unsigned short f32_to_bf16(float f) {
    union { float f; uint32_t u; } v; v.f = f;
    uint32_t u = v.u;
    u += 0x7FFFu + ((u >> 16) & 1u);   // round-to-nearest-even
    return (unsigned short)(u >> 16);
}

// Raw hardware exp2: args in [-28.6, 0.03] (normal range), ~1 ulp.
__device__ inline float fast_exp2(float x) {
    float r;
    asm("v_exp_f32 %0, %1" : "=v"(r) : "v"(x));
    return r;
}

// ---------------- Kernel 1: normalize rows -> bf16, l_pos ----------------
__global__ __launch_bounds__(256) void prep_kernel(
    const float* __restrict__ q, const float* __restrict__ k,
    unsigned short* __restrict__ qb, unsigned short* __restrict__ kb,
    float* __restrict__ lposT) {
    const int wid  = threadIdx.x >> 6;
    const int lane = threadIdx.x & 63;
    const int row  = blockIdx.x * 4 + wid;

    const float4 qv = *reinterpret_cast<const float4*>(q + (size_t)row * DIM + lane * 4);
    const float4 kv = *reinterpret_cast<const float4*>(k + (size_t)row * DIM + lane * 4);

    float qq = qv.x*qv.x + qv.y*qv.y + qv.z*qv.z + qv.w*qv.w;
    float kk = kv.x*kv.x + kv.y*kv.y + kv.z*kv.z + kv.w*kv.w;
    float qk = qv.x*kv.x + qv.y*kv.y + qv.z*kv.z + qv.w*kv.w;

    #pragma unroll
    for (int off = 32; off > 0; off >>= 1) {
        qq += __shfl_xor(qq, off, 64);
        kk += __shfl_xor(kk, off, 64);
        qk += __shfl_xor(qk, off, 64);
    }
    const float iq = 1.0f / sqrtf(qq);
    const float ik = 1.0f / sqrtf(kk);

    ushort4 qs, ks;
    qs.x = f32_to_bf16(qv.x * iq); qs.y = f32_to_bf16(qv.y * iq);
    qs.z = f32_to_bf16(qv.z * iq); qs.w = f32_to_bf16(qv.w * iq);
    ks.x = f32_to_bf16(kv.x * ik); ks.y = f32_to_bf16(kv.y * ik);
    ks.z = f32_to_bf16(kv.z * ik); ks.w = f32_to_bf16(kv.w * ik);
    *reinterpret_cast<ushort4*>(qb + (size_t)row * DIM + lane * 4) = qs;
    *reinterpret_cast<ushort4*>(kb + (size_t)row * DIM + lane * 4) = ks;

    if (lane == 0) lposT[row] = qk * iq * ik * INV_T;
}

// ---------------- Kernel 2: persistent K-strip GEMM + fused exp-sum ----------
// A = K rows (LDS), B = Q rows (regs, 32 unique per wave). Triple-buffered
// ring, 2-tiles-ahead prefetch (vmcnt(8)), 2 raw barriers/kstep. LDS tile =
// 64 Krows x 128 dims stored as [128 layout-rows][64 dims] (128B rows, the
// round-2..5 zero-conflict layout). Epilogue deferred one chunk; setprio(1)
// around MFMA clusters.
__global__ __launch_bounds__(256, 3) void gemm_lse_kernel(
    const unsigned short* __restrict__ qb, const unsigned short* __restrict__ kb,
    float* __restrict__ ps) {
    __shared__ char lds[3 * 16384];

    const int tid  = threadIdx.x;
    const int lane = tid & 63;
    const int wid  = tid >> 6;
    const int g    = lane >> 4;      // 0..3
    const int r16  = lane & 15;
    const int xr   = r16 & 7;

    const int strip   = blockIdx.x;        // 0..15 (x%8 -> XCD by dispatch order)
    const int qtile   = blockIdx.y;        // 0..63
    const int qbase   = qtile * 128;
    const int qw      = qbase + wid * 32;  // this wave's 32 unique Q rows
    const int kstrip0 = strip * 512;

    // staging map: issue i covers layout rows [i*32, i*32+32); srow = tid>>3,
    // pre-swizzled source slot (tid&7)^(srow&7). LayoutRow r<64 = Krow r,
    // dims[0:64) of tile; r>=64 = Krow r-64, dims[64:128).
    const int srow  = tid >> 3;                 // 0..31
    const int sslot = (tid & 7) ^ (srow & 7);   // inverse-swizzle SOURCE
    const int ldsOff = wid * 1024;

    // tile t: Krows [kstrip0+(t>>1)*64, +64), dims [(t&1)*128, +128)
    auto stage = [&](int tile, char* dst) {
        const int krow0 = kstrip0 + (tile >> 1) * 64;
        const int dim0  = (tile & 1) * 128;
        #pragma unroll
        for (int i = 0; i < 4; ++i) {
            const int krow = krow0 + (i & 1) * 32 + srow;
            const int dim  = dim0 + (i >> 1) * 64 + sslot * 8;
            const unsigned short* gp = kb + (size_t)krow * DIM + dim;
            __builtin_amdgcn_global_load_lds(
                (const __attribute__((address_space(1))) void*)gp,
                (__attribute__((address_space(3))) void*)(dst + i * 4096 + ldsOff),
                16, 0, 0);
        }
    };

    // ---- Q fragments straight from global (L2-resident, 16 x 16B per lane) ----
    bf16x8 qf[8][2];   // [global dim-slice 0..7][j: 16-row half]
    #pragma unroll
    for (int s = 0; s < 8; ++s)
        #pragma unroll
        for (int j = 0; j < 2; ++j)
            qf[s][j] = *reinterpret_cast<const bf16x8*>(
                qb + (size_t)(qw + j * 16 + r16) * DIM + s * 32 + g * 8);

    char* const B0 = lds;
    char* const B1 = lds + 16384;
    char* const B2 = lds + 32768;
    char* const bufs[3] = {B0, B1, B2};

    stage(0, B0);
    stage(1, B1);
    asm volatile("s_waitcnt vmcnt(0)" ::: "memory");   // one-time full drain
    __syncthreads();

    f32x4 acc[4][2] = {};                  // [i: Krow/16][j: Q 16-row half]
    float ssum[2] = {0.f, 0.f};

    // one kstep: 64 Krows x 128 dims from LDS vs qf slices sbase..sbase+3
    auto mfma_kstep = [&](const char* src, int sbase) {
        #pragma unroll
        for (int kk = 0; kk < 4; ++kk) {
            bf16x8 a[4];
            #pragma unroll
            for (int i = 0; i < 4; ++i) {
                const int lrow = (kk >> 1) * 64 + i * 16 + r16;
                a[i] = *reinterpret_cast<const bf16x8*>(
                    src + lrow * 128 + (((((kk & 1) << 2) | g) ^ xr) << 4));
            }
            #pragma unroll
            for (int i = 0; i < 4; ++i)
                #pragma unroll
                for (int j = 0; j < 2; ++j)
                    acc[i][j] = __builtin_amdgcn_mfma_f32_16x16x32_bf16(
                        a[i], qf[sbase + kk][j], acc[i][j], 0, 0, 0);
        }
    };

    // deferred per-chunk epilogue: exp-accumulate acc (64 Krows done), zero acc
    auto epilogue = [&](int c) {
        const int kc0  = kstrip0 + c * 64;
        const bool diag = (kc0 >> 6) == (qw >> 6);   // wave-uniform
        #pragma unroll
        for (int j = 0; j < 2; ++j) {
            float s = 0.f;
            if (diag) {
                const int grow = qw + j * 16 + r16;
                #pragma unroll
                for (int i = 0; i < 4; ++i)
                    #pragma unroll
                    for (int r = 0; r < 4; ++r) {
                        float e = fast_exp2(fmaf(acc[i][j][r], C1, C0));
                        if (grow == kc0 + i * 16 + g * 4 + r) e = 0.f;
                        s += e;
                    }
            } else {
                #pragma unroll
                for (int i = 0; i < 4; ++i)
                    #pragma unroll
                    for (int r = 0; r < 4; ++r)
                        s += fast_exp2(fmaf(acc[i][j][r], C1, C0));
            }
            ssum[j] += s;
        }
        #pragma unroll
        for (int i = 0; i < 4; ++i) {
            acc[i][0] = f32x4{0.f, 0.f, 0.f, 0.f};
            acc[i][1] = f32x4{0.f, 0.f, 0.f, 0.f};
        }
    };

    // ---- main loop: 16 tiles, ring of 3 buffers, 2-ahead prefetch ----
    #pragma unroll
    for (int t = 0; t < 16; ++t) {
        __builtin_amdgcn_s_barrier();          // A: all waves done computing t-1
                                               //    -> safe to overwrite B[(t+2)%3]
        if (t + 2 < 16) stage(t + 2, bufs[(t + 2) % 3]);
        if ((t & 1) == 0 && t >= 2) epilogue((t >> 1) - 1);  // reg-only, overlaps loads
        if (t <= 13)      { asm volatile("s_waitcnt vmcnt(8)" ::: "memory"); }
        else if (t == 14) { asm volatile("s_waitcnt vmcnt(4)" ::: "memory"); }
        else              { asm volatile("s_waitcnt vmcnt(0)" ::: "memory"); }
        __builtin_amdgcn_s_barrier();          // B: tile t fully in LDS for all
        __builtin_amdgcn_sched_barrier(0);
        __builtin_amdgcn_s_setprio(1);
        mfma_kstep(bufs[t % 3], (t & 1) * 4);
        __builtin_amdgcn_s_setprio(0);
    }
    epilogue(7);   // last chunk

    // ---- wave-local reduction over g-groups, direct store ----
    #pragma unroll
    for (int j = 0; j < 2; ++j) {
        float s = ssum[j];
        s += __shfl_xor(s, 16, 64);
        s += __shfl_xor(s, 32, 64);
        if (g == 0)
            ps[(size_t)(qw + j * 16 + r16) * 16 + strip] = s;
    }
}

// ---------------- Kernel 3: combine 16 strip partials -> loss ----------------
__global__ __launch_bounds__(256) void finalize_kernel(
    const float* __restrict__ ps, const float* __restrict__ lposT,
    float* __restrict__ out) {
    const int row = blockIdx.x * 256 + threadIdx.x;
    float S = 0.f;
    #pragma unroll
    for (int c = 0; c < 4; ++c) {
        const float4 p = *reinterpret_cast<const float4*>(ps + (size_t)row * 16 + c * 4);
        S += p.x + p.y + p.z + p.w;
    }
    const float lp = lposT[row];
    S += __expf(lp - M0);
    out[row] = M0 + logf(S) - lp;
}

extern "C" void kernel_launch(void* const* d_in, const int* in_sizes, int n_in,
                              void* d_out, int out_size, void* d_ws, size_t ws_size,
                              hipStream_t stream) {
    const float* q = (const float*)d_in[0];
    const float* k = (const float*)d_in[1];
    float* out = (float*)d_out;

    char* ws = (char*)d_ws;
    unsigned short* qb  = (unsigned short*)(ws);                      // 4 MB
    unsigned short* kb  = (unsigned short*)(ws + (4u << 20));         // 4 MB
    float*          lpt = (float*)(ws + (8u << 20));                  // 32 KB
    float*          ps  = (float*)(ws + (8u << 20) + (32u << 10));    // 512 KB

    prep_kernel<<<N_ROWS / 4, 256, 0, stream>>>(q, k, qb, kb, lpt);
    dim3 grid(16, 64);   // x = strip (x%8 -> XCD), y = Q-tile
    gemm_lse_kernel<<<grid, 256, 0, stream>>>(qb, kb, ps);
    finalize_kernel<<<N_ROWS / 256, 256, 0, stream>>>(ps, lpt, out);
}